// Round 4
// baseline (1191.444 us; speedup 1.0000x reference)
//
#include <hip/hip_runtime.h>
#include <hip/hip_bf16.h>
#include <stdint.h>

// Problem constants
#define T_TOK 8192      // B*S tokens
#define DMODEL 1024
#define FFDIM 4096
#define NEXP 8
#define TOPK 2
#define MTILES 136              // ceil-padded 128-row tiles: 16384 + 8*127 <= 136*128
#define ROWS_PAD (MTILES * 128) // 17408

typedef __bf16 bf16x8 __attribute__((ext_vector_type(8)));
typedef float f32x4 __attribute__((ext_vector_type(4)));

__device__ __forceinline__ unsigned short f2bf(float f) {
    union { float f; unsigned u; } v; v.f = f;
    unsigned u = v.u;
    u += 0x7fffu + ((u >> 16) & 1u);   // round-to-nearest-even
    return (unsigned short)(u >> 16);
}

__device__ __forceinline__ ushort4 cvt4(const float4 v) {
    ushort4 o;
    o.x = f2bf(v.x); o.y = f2bf(v.y); o.z = f2bf(v.z); o.w = f2bf(v.w);
    return o;
}

// ---------------- fused prep: zero-init + all fp32->bf16 conversions ---------
// One launch, 4096 blocks, grid-stride everywhere (replaces init + 3x cvt:
// those were 100K one-float4 blocks; dispatch overhead suspected as the bulk
// of the ~430us non-GEMM time).
__global__ __launch_bounds__(256)
void prep_kernel(const float* __restrict__ x, const float* __restrict__ w1,
                 const float* __restrict__ w2,
                 float* __restrict__ out0, unsigned short* __restrict__ xb,
                 unsigned short* __restrict__ w1b, unsigned short* __restrict__ w2b,
                 int* __restrict__ row_token, unsigned short* __restrict__ zero_row,
                 int* __restrict__ cnt_fill) {
    const int nth = gridDim.x * blockDim.x;
    const int t0 = blockIdx.x * blockDim.x + threadIdx.x;
    const float4 z4 = make_float4(0.f, 0.f, 0.f, 0.f);
    for (int i = t0; i < T_TOK * DMODEL / 4; i += nth) ((float4*)out0)[i] = z4;
    for (int i = t0; i < T_TOK * DMODEL / 4; i += nth)
        ((ushort4*)xb)[i] = cvt4(((const float4*)x)[i]);
    for (int i = t0; i < NEXP * FFDIM * DMODEL / 4; i += nth)
        ((ushort4*)w1b)[i] = cvt4(((const float4*)w1)[i]);
    for (int i = t0; i < NEXP * DMODEL * FFDIM / 4; i += nth)
        ((ushort4*)w2b)[i] = cvt4(((const float4*)w2)[i]);
    for (int i = t0; i < ROWS_PAD; i += nth) row_token[i] = -1;
    for (int i = t0; i < DMODEL; i += nth) zero_row[i] = 0;
    for (int i = t0; i < 32; i += nth) cnt_fill[i] = 0;
}

// ---------------- gating: one wave per token, fp64 accumulation --------------
__global__ __launch_bounds__(256)
void gate_kernel(const float* __restrict__ x, const float* __restrict__ wg,
                 const float* __restrict__ bg,
                 float* __restrict__ out_idx, float* __restrict__ out_val,
                 int* __restrict__ tok_e, float* __restrict__ tok_g, int* __restrict__ cnt) {
    int t = blockIdx.x * 4 + (threadIdx.x >> 6);
    int lane = threadIdx.x & 63;
    const float4* xr = (const float4*)(x + (size_t)t * DMODEL);
    double acc[NEXP];
#pragma unroll
    for (int e = 0; e < NEXP; ++e) acc[e] = 0.0;
#pragma unroll
    for (int it = 0; it < 4; ++it) {
        float4 xv = xr[lane + it * 64];
#pragma unroll
        for (int e = 0; e < NEXP; ++e) {
            float4 wv = ((const float4*)(wg + e * DMODEL))[lane + it * 64];
            acc[e] += (double)xv.x * wv.x + (double)xv.y * wv.y +
                      (double)xv.z * wv.z + (double)xv.w * wv.w;
        }
    }
#pragma unroll
    for (int off = 32; off; off >>= 1)
#pragma unroll
        for (int e = 0; e < NEXP; ++e) acc[e] += __shfl_down(acc[e], off, 64);
    if (lane == 0) {
        double lg[NEXP], mx = -1e300;
#pragma unroll
        for (int e = 0; e < NEXP; ++e) { lg[e] = acc[e] + (double)bg[e]; mx = lg[e] > mx ? lg[e] : mx; }
        double p[NEXP], s = 0.0;
#pragma unroll
        for (int e = 0; e < NEXP; ++e) { p[e] = exp(lg[e] - mx); s += p[e]; }
#pragma unroll
        for (int e = 0; e < NEXP; ++e) p[e] /= s;
        int i0 = 0;
#pragma unroll
        for (int e = 1; e < NEXP; ++e) if (p[e] > p[i0]) i0 = e;
        int i1 = (i0 == 0) ? 1 : 0;
#pragma unroll
        for (int e = 0; e < NEXP; ++e) if (e != i0 && p[e] > p[i1]) i1 = e;
        out_idx[t * 2 + 0] = (float)i0;
        out_idx[t * 2 + 1] = (float)i1;
        out_val[t * 2 + 0] = (float)p[i0];
        out_val[t * 2 + 1] = (float)p[i1];
        tok_e[t * 2 + 0] = i0; tok_e[t * 2 + 1] = i1;
        tok_g[t * 2 + 0] = (float)p[i0]; tok_g[t * 2 + 1] = (float)p[i1];
        atomicAdd(&cnt[i0], 1);
        atomicAdd(&cnt[i1], 1);
    }
}

// ---------------- 128-padded segment offsets ---------------------------------
__global__ void offsets_kernel(const int* __restrict__ cnt, int* __restrict__ off_pad) {
    if (threadIdx.x == 0 && blockIdx.x == 0) {
        int o = 0;
        off_pad[0] = 0;
#pragma unroll
        for (int e = 0; e < NEXP; ++e) {
            o += ((cnt[e] + 127) >> 7) << 7;
            off_pad[e + 1] = o;
        }
    }
}

// ---------------- scatter tokens into padded row space -----------------------
__global__ void scatter_kernel(const int* __restrict__ tok_e, const float* __restrict__ tok_g,
                               const int* __restrict__ off_pad, int* __restrict__ fill,
                               int* __restrict__ row_token, float* __restrict__ row_gate) {
    int i = blockIdx.x * blockDim.x + threadIdx.x;
    if (i < T_TOK * TOPK) {
        int e = tok_e[i];
        int pos = off_pad[e] + atomicAdd(&fill[e], 1);
        row_token[pos] = i >> 1;
        row_gate[pos] = tok_g[i];
    }
}

// ---------------- grouped GEMM: 128x128 tile, BK=32, ring-4, counted vmcnt ---
// C = A * W^T. 256 thr = 4 waves (2M x 2N), per-wave output 64x64, acc 4x4.
// LDS: ring of 4 x (128 A-rows + 128 B-rows) x 32 cols bf16 = 64 KiB
// -> 2 blocks/CU co-resident (R0's geometry; m114 cross-block MFMA/mem
// overlap) PLUS the R2 deep pipeline (3-tile lookahead, counted vmcnt).
// Per K-tile: 2 fine phases {ds_read frags; stage(t+3) half; s_barrier;
// lgkmcnt(0); setprio(1); 8 MFMA; setprio(0); s_barrier}; tile end: counted
// s_waitcnt vmcnt(8) (4 loads/thread/tile, 12 in flight max) + barrier.
// Race safety: stage(t+3) overwrites slot[(t-1)&3]; reads of tile t-1
// completed before tile t-1's lgkmcnt(0), which precedes the barrier chain
// leading to this stage.
// XCD swizzle (T1, bijective: nwg % 8 == 0): hw block id -> xcd = id&7,
// slot = id>>3, wid = xcd*(nwg/8)+slot; m-tile = wid % MTILES (fastest).
// Each XCD runs consecutive M-tiles at a fixed N-panel -> W-panel L2-hot.
// MODE 0: A = gathered x_bf16 rows, store h = leakyrelu(C + b1) as bf16
// MODE 1: A = h rows, atomicAdd gate*(C + b2) into out
template <int MODE, int KD, int ND, int YD>
__global__ __launch_bounds__(256)
void moe_gemm(const unsigned short* __restrict__ A, const unsigned short* __restrict__ W,
              const float* __restrict__ bias, const int* __restrict__ row_token,
              const float* __restrict__ row_gate, const int* __restrict__ off_pad,
              const unsigned short* __restrict__ zero_row,
              unsigned short* __restrict__ Hout, float* __restrict__ Out) {
    __shared__ __attribute__((aligned(16))) unsigned short As[4 * 128 * 32];
    __shared__ __attribute__((aligned(16))) unsigned short Bs[4 * 128 * 32];
    constexpr int NWG = MTILES * YD;
    constexpr int NT = KD / 32;
    static_assert(NWG % 8 == 0, "bijective XCD swizzle needs nwg % 8 == 0");

    // XCD-chunked bijective remap (T1)
    const int id = blockIdx.x;
    const int wid = (id & 7) * (NWG / 8) + (id >> 3);
    const int m0 = (wid % MTILES) * 128;
    const int n0 = (wid / MTILES) * 128;

    // expert for this row tile (off_pad monotone; last true wins)
    int e = 0;
#pragma unroll
    for (int q = 0; q < NEXP - 1; ++q)
        if (off_pad[q + 1] <= m0) e = q + 1;

    const int tid = threadIdx.x;
    const int wave = tid >> 6;
    const int lane = tid & 63;
    const int wm = wave >> 1, wn = wave & 1;
    const int lane15 = lane & 15;
    const int quad = lane >> 4;

    // staging geometry: 128 rows x 4 chunks (16B) per matrix = 512 chunks,
    // 2 rounds of 256 threads. row = rr*64 + (tid>>2), logical chunk = tid&3.
    // swizzled source chunk: (tid&3) ^ ((row>>1)&3), rr-invariant.
    const int scol = (tid & 3) ^ ((tid >> 3) & 3);

    const unsigned short* aptr[2];
    const unsigned short* bptr[2];
#pragma unroll
    for (int rr = 0; rr < 2; ++rr) {
        int row = rr * 64 + (tid >> 2);
        const unsigned short* ab;
        if (MODE == 0) {
            int tok = row_token[m0 + row];
            ab = (tok < 0) ? zero_row : (A + (size_t)tok * KD);
        } else {
            ab = A + (size_t)(m0 + row) * KD;
        }
        aptr[rr] = ab + scol * 8;
        bptr[rr] = W + ((size_t)e * ND + (size_t)(n0 + row)) * (size_t)KD + scol * 8;
    }

    f32x4 acc[4][4];
#pragma unroll
    for (int i = 0; i < 4; ++i)
#pragma unroll
        for (int j = 0; j < 4; ++j) acc[i][j] = (f32x4)0.f;

    const int rowA = wm * 64 + lane15;     // + i*16 per fragment
    const int rowB = wn * 64 + lane15;     // + j*16 per fragment
    const int pcs = ((quad ^ ((lane15 >> 1) & 3)) * 8);  // physical chunk (shorts)

    auto stageA = [&](int tt) {
        const int bo = (tt & 3) * 4096;
        const int koff = tt * 32;
#pragma unroll
        for (int rr = 0; rr < 2; ++rr)
            __builtin_amdgcn_global_load_lds(
                (const __attribute__((address_space(1))) void*)(aptr[rr] + koff),
                (__attribute__((address_space(3))) void*)(As + bo + (rr * 256 + wave * 64) * 8), 16, 0, 0);
    };
    auto stageB = [&](int tt) {
        const int bo = (tt & 3) * 4096;
        const int koff = tt * 32;
#pragma unroll
        for (int rr = 0; rr < 2; ++rr)
            __builtin_amdgcn_global_load_lds(
                (const __attribute__((address_space(1))) void*)(bptr[rr] + koff),
                (__attribute__((address_space(3))) void*)(Bs + bo + (rr * 256 + wave * 64) * 8), 16, 0, 0);
    };

    // prologue: fill 3 ring slots (12 loads in flight), certify tile 0
    stageA(0); stageB(0); stageA(1); stageB(1); stageA(2); stageB(2);
    asm volatile("s_waitcnt vmcnt(8)" ::: "memory");
    __builtin_amdgcn_s_barrier();

    for (int t = 0; t < NT; ++t) {
        const int bo = (t & 3) * 4096;
        // -------- phase 0: acc rows i=0,1 --------
        bf16x8 af0[2], bfv[4];
#pragma unroll
        for (int i = 0; i < 2; ++i)
            af0[i] = *(const bf16x8*)(As + bo + (rowA + i * 16) * 32 + pcs);
#pragma unroll
        for (int j = 0; j < 4; ++j)
            bfv[j] = *(const bf16x8*)(Bs + bo + (rowB + j * 16) * 32 + pcs);
        if (t + 3 < NT) stageA(t + 3);
        __builtin_amdgcn_s_barrier();
        asm volatile("s_waitcnt lgkmcnt(0)" ::: "memory");
        __builtin_amdgcn_s_setprio(1);
#pragma unroll
        for (int i = 0; i < 2; ++i)
#pragma unroll
            for (int j = 0; j < 4; ++j)
                acc[i][j] = __builtin_amdgcn_mfma_f32_16x16x32_bf16(af0[i], bfv[j], acc[i][j], 0, 0, 0);
        __builtin_amdgcn_s_setprio(0);
        __builtin_amdgcn_s_barrier();
        // -------- phase 1: acc rows i=2,3 (bfv reused from registers) --------
        bf16x8 af1[2];
#pragma unroll
        for (int i = 0; i < 2; ++i)
            af1[i] = *(const bf16x8*)(As + bo + (rowA + 32 + i * 16) * 32 + pcs);
        if (t + 3 < NT) stageB(t + 3);
        __builtin_amdgcn_s_barrier();
        asm volatile("s_waitcnt lgkmcnt(0)" ::: "memory");
        __builtin_amdgcn_s_setprio(1);
#pragma unroll
        for (int i = 0; i < 2; ++i)
#pragma unroll
            for (int j = 0; j < 4; ++j)
                acc[2 + i][j] = __builtin_amdgcn_mfma_f32_16x16x32_bf16(af1[i], bfv[j], acc[2 + i][j], 0, 0, 0);
        __builtin_amdgcn_s_setprio(0);
        // -------- tile end: certify tile t+1 with counted vmcnt --------
        if (t < NT - 1) {
            if (t < NT - 3)       asm volatile("s_waitcnt vmcnt(8)" ::: "memory");
            else if (t == NT - 3) asm volatile("s_waitcnt vmcnt(4)" ::: "memory");
            else                  asm volatile("s_waitcnt vmcnt(0)" ::: "memory");
            __builtin_amdgcn_s_barrier();
        }
    }

    // epilogue — note rowA/rowB are wm*64/wn*64 based; fragment i covers
    // rows {0,16} and {32,48} within the wave's 64-row strip.
    float bv[4];
#pragma unroll
    for (int j = 0; j < 4; ++j)
        bv[j] = bias[e * ND + n0 + wn * 64 + j * 16 + lane15];
#pragma unroll
    for (int i = 0; i < 4; ++i) {
        const int mrow = (i < 2) ? (i * 16) : (32 + (i - 2) * 16);
#pragma unroll
        for (int r4 = 0; r4 < 4; ++r4) {
            int m = m0 + wm * 64 + mrow + quad * 4 + r4;
            int tok = 0; float g = 0.f;
            if (MODE == 1) { tok = row_token[m]; g = row_gate[m]; }
#pragma unroll
            for (int j = 0; j < 4; ++j) {
                int n = n0 + wn * 64 + j * 16 + lane15;
                float v = acc[i][j][r4] + bv[j];
                if (MODE == 0) {
                    v = v > 0.f ? v : 0.1f * v;
                    Hout[(size_t)m * ND + n] = f2bf(v);
                } else {
                    if (tok >= 0) atomicAdd(Out + (size_t)tok * ND + n, g * v);
                }
            }
        }
    }
}

extern "C" void kernel_launch(void* const* d_in, const int* in_sizes, int n_in,
                              void* d_out, int out_size, void* d_ws, size_t ws_size,
                              hipStream_t stream) {
    const float* x  = (const float*)d_in[0];
    const float* wg = (const float*)d_in[1];
    const float* bg = (const float*)d_in[2];
    const float* w1 = (const float*)d_in[3];
    const float* b1 = (const float*)d_in[4];
    const float* w2 = (const float*)d_in[5];
    const float* b2 = (const float*)d_in[6];
    float* out0 = (float*)d_out;
    float* out_idx = out0 + (size_t)T_TOK * DMODEL;
    float* out_val = out_idx + T_TOK * TOPK;

    char* p = (char*)d_ws;
    auto alloc = [&](size_t bytes) {
        char* q = p;
        p += (bytes + 255) & ~(size_t)255;
        return q;
    };
    unsigned short* xb  = (unsigned short*)alloc((size_t)T_TOK * DMODEL * 2);
    unsigned short* w1b = (unsigned short*)alloc((size_t)NEXP * FFDIM * DMODEL * 2);
    unsigned short* w2b = (unsigned short*)alloc((size_t)NEXP * DMODEL * FFDIM * 2);
    unsigned short* hb  = (unsigned short*)alloc((size_t)ROWS_PAD * FFDIM * 2);
    unsigned short* zrow = (unsigned short*)alloc(DMODEL * 2);
    int* cnt = (int*)alloc(128);  // cnt[8] + fill[8]
    int* fill = cnt + 8;
    int* off_pad = (int*)alloc(64);
    int* tok_e = (int*)alloc((size_t)T_TOK * TOPK * 4);
    float* tok_g = (float*)alloc((size_t)T_TOK * TOPK * 4);
    int* row_token = (int*)alloc((size_t)ROWS_PAD * 4);
    float* row_gate = (float*)alloc((size_t)ROWS_PAD * 4);
    if ((size_t)(p - (char*)d_ws) > ws_size) return;  // ws too small: fail visibly, no OOB

    prep_kernel<<<4096, 256, 0, stream>>>(x, w1, w2, out0, xb, w1b, w2b,
                                          row_token, zrow, cnt);
    gate_kernel<<<T_TOK / 4, 256, 0, stream>>>(x, wg, bg, out_idx, out_val, tok_e, tok_g, cnt);
    offsets_kernel<<<1, 64, 0, stream>>>(cnt, off_pad);
    scatter_kernel<<<(T_TOK * TOPK + 255) / 256, 256, 0, stream>>>(tok_e, tok_g, off_pad, fill, row_token, row_gate);
    moe_gemm<0, DMODEL, FFDIM, FFDIM / 128><<<MTILES * (FFDIM / 128), 256, 0, stream>>>(
        xb, w1b, b1, row_token, row_gate, off_pad, zrow, hb, nullptr);
    moe_gemm<1, FFDIM, DMODEL, DMODEL / 128><<<MTILES * (DMODEL / 128), 256, 0, stream>>>(
        hb, w2b, b2, row_token, row_gate, off_pad, zrow, nullptr, out0);
}

// Round 5
// 1105.997 us; speedup vs baseline: 1.0773x; 1.0773x over previous
//
#include <hip/hip_runtime.h>
#include <hip/hip_bf16.h>
#include <stdint.h>

// Problem constants
#define T_TOK 8192      // B*S tokens
#define DMODEL 1024
#define FFDIM 4096
#define NEXP 8
#define TOPK 2
#define MTILES 136              // ceil-padded 128-row tiles: 16384 + 8*127 <= 136*128
#define ROWS_PAD (MTILES * 128) // 17408

typedef __bf16 bf16x8 __attribute__((ext_vector_type(8)));
typedef float f32x4 __attribute__((ext_vector_type(4)));

__device__ __forceinline__ unsigned short f2bf(float f) {
    union { float f; unsigned u; } v; v.f = f;
    unsigned u = v.u;
    u += 0x7fffu + ((u >> 16) & 1u);   // round-to-nearest-even
    return (unsigned short)(u >> 16);
}

__device__ __forceinline__ ushort4 cvt4(const float4 v) {
    ushort4 o;
    o.x = f2bf(v.x); o.y = f2bf(v.y); o.z = f2bf(v.z); o.w = f2bf(v.w);
    return o;
}

// ---------------- fused prep: zero-init + all fp32->bf16 conversions ---------
__global__ __launch_bounds__(256)
void prep_kernel(const float* __restrict__ x, const float* __restrict__ w1,
                 const float* __restrict__ w2,
                 float* __restrict__ out0, unsigned short* __restrict__ xb,
                 unsigned short* __restrict__ w1b, unsigned short* __restrict__ w2b,
                 int* __restrict__ row_token, unsigned short* __restrict__ zero_row,
                 int* __restrict__ cnt_fill) {
    const int nth = gridDim.x * blockDim.x;
    const int t0 = blockIdx.x * blockDim.x + threadIdx.x;
    const float4 z4 = make_float4(0.f, 0.f, 0.f, 0.f);
    for (int i = t0; i < T_TOK * DMODEL / 4; i += nth) ((float4*)out0)[i] = z4;
    for (int i = t0; i < T_TOK * DMODEL / 4; i += nth)
        ((ushort4*)xb)[i] = cvt4(((const float4*)x)[i]);
    for (int i = t0; i < NEXP * FFDIM * DMODEL / 4; i += nth)
        ((ushort4*)w1b)[i] = cvt4(((const float4*)w1)[i]);
    for (int i = t0; i < NEXP * DMODEL * FFDIM / 4; i += nth)
        ((ushort4*)w2b)[i] = cvt4(((const float4*)w2)[i]);
    for (int i = t0; i < ROWS_PAD; i += nth) row_token[i] = -1;
    for (int i = t0; i < DMODEL; i += nth) zero_row[i] = 0;
    for (int i = t0; i < 32; i += nth) cnt_fill[i] = 0;
}

// ---------------- gating: one wave per token, fp64 accumulation --------------
__global__ __launch_bounds__(256)
void gate_kernel(const float* __restrict__ x, const float* __restrict__ wg,
                 const float* __restrict__ bg,
                 float* __restrict__ out_idx, float* __restrict__ out_val,
                 int* __restrict__ tok_e, float* __restrict__ tok_g, int* __restrict__ cnt) {
    int t = blockIdx.x * 4 + (threadIdx.x >> 6);
    int lane = threadIdx.x & 63;
    const float4* xr = (const float4*)(x + (size_t)t * DMODEL);
    double acc[NEXP];
#pragma unroll
    for (int e = 0; e < NEXP; ++e) acc[e] = 0.0;
#pragma unroll
    for (int it = 0; it < 4; ++it) {
        float4 xv = xr[lane + it * 64];
#pragma unroll
        for (int e = 0; e < NEXP; ++e) {
            float4 wv = ((const float4*)(wg + e * DMODEL))[lane + it * 64];
            acc[e] += (double)xv.x * wv.x + (double)xv.y * wv.y +
                      (double)xv.z * wv.z + (double)xv.w * wv.w;
        }
    }
#pragma unroll
    for (int off = 32; off; off >>= 1)
#pragma unroll
        for (int e = 0; e < NEXP; ++e) acc[e] += __shfl_down(acc[e], off, 64);
    if (lane == 0) {
        double lg[NEXP], mx = -1e300;
#pragma unroll
        for (int e = 0; e < NEXP; ++e) { lg[e] = acc[e] + (double)bg[e]; mx = lg[e] > mx ? lg[e] : mx; }
        double p[NEXP], s = 0.0;
#pragma unroll
        for (int e = 0; e < NEXP; ++e) { p[e] = exp(lg[e] - mx); s += p[e]; }
#pragma unroll
        for (int e = 0; e < NEXP; ++e) p[e] /= s;
        int i0 = 0;
#pragma unroll
        for (int e = 1; e < NEXP; ++e) if (p[e] > p[i0]) i0 = e;
        int i1 = (i0 == 0) ? 1 : 0;
#pragma unroll
        for (int e = 0; e < NEXP; ++e) if (e != i0 && p[e] > p[i1]) i1 = e;
        out_idx[t * 2 + 0] = (float)i0;
        out_idx[t * 2 + 1] = (float)i1;
        out_val[t * 2 + 0] = (float)p[i0];
        out_val[t * 2 + 1] = (float)p[i1];
        tok_e[t * 2 + 0] = i0; tok_e[t * 2 + 1] = i1;
        tok_g[t * 2 + 0] = (float)p[i0]; tok_g[t * 2 + 1] = (float)p[i1];
        atomicAdd(&cnt[i0], 1);
        atomicAdd(&cnt[i1], 1);
    }
}

// ---------------- 128-padded segment offsets ---------------------------------
__global__ void offsets_kernel(const int* __restrict__ cnt, int* __restrict__ off_pad) {
    if (threadIdx.x == 0 && blockIdx.x == 0) {
        int o = 0;
        off_pad[0] = 0;
#pragma unroll
        for (int e = 0; e < NEXP; ++e) {
            o += ((cnt[e] + 127) >> 7) << 7;
            off_pad[e + 1] = o;
        }
    }
}

// ---------------- scatter tokens into padded row space -----------------------
__global__ void scatter_kernel(const int* __restrict__ tok_e, const float* __restrict__ tok_g,
                               const int* __restrict__ off_pad, int* __restrict__ fill,
                               int* __restrict__ row_token, float* __restrict__ row_gate) {
    int i = blockIdx.x * blockDim.x + threadIdx.x;
    if (i < T_TOK * TOPK) {
        int e = tok_e[i];
        int pos = off_pad[e] + atomicAdd(&fill[e], 1);
        row_token[pos] = i >> 1;
        row_gate[pos] = tok_g[i];
    }
}

// ---------------- grouped GEMM: 128(M)x256(N) tile, BK=32, dbuf-2 ------------
// C = A * W^T. R0's PROVEN inner loop (2-deep LDS double-buffer, one
// __syncthreads drain per K-step, verified 0-conflict chunk-XOR swizzle),
// with ONLY the tile geometry changed 128x128 -> 128x256:
//   - A-panel re-reads halve (n-tile count halves): staged bytes/GEMM
//     2.23 GB -> 1.66 GB, HBM fetch of hb drops ~40%.
//   - 32 MFMA/wave per K-step (vs 16) amortizes the per-iter drain 2x.
// 4 waves (2M x 2N), per-wave output 64x128, acc[4][8]. LDS = 2 bufs x
// (128 A-rows + 256 B-rows) x 32 cols bf16 = 48 KB -> 2 blocks/CU retained
// (m114 cross-block overlap is what hides the drain latency).
// Loads for iter k+1 issue right after iter k's barrier (~1 iter of age at
// the next drain). Swizzle: physical chunk = logical chunk ^ ((row>>1)&3);
// row offsets in both stage and read paths are multiples of 16 -> the lane
// formula pcs = (quad ^ ((lane15>>1)&3))*8 is unchanged (0 conflicts, R0).
// MODE 0: A = gathered x_bf16 rows, store h = leakyrelu(C + b1) as bf16
// MODE 1: A = h rows, atomicAdd gate*(C + b2) into out
template <int MODE, int KD, int ND>
__global__ __launch_bounds__(256, 2)
void moe_gemm(const unsigned short* __restrict__ A, const unsigned short* __restrict__ W,
              const float* __restrict__ bias, const int* __restrict__ row_token,
              const float* __restrict__ row_gate, const int* __restrict__ off_pad,
              const unsigned short* __restrict__ zero_row,
              unsigned short* __restrict__ Hout, float* __restrict__ Out) {
    __shared__ __attribute__((aligned(16))) unsigned short As[2 * 128 * 32];
    __shared__ __attribute__((aligned(16))) unsigned short Bs[2 * 256 * 32];
    const int m0 = blockIdx.x * 128;
    const int n0 = blockIdx.y * 256;

    // expert for this row tile (off_pad monotone; last true wins)
    int e = 0;
#pragma unroll
    for (int q = 0; q < NEXP - 1; ++q)
        if (off_pad[q + 1] <= m0) e = q + 1;

    const int tid = threadIdx.x;
    const int wave = tid >> 6;
    const int lane = tid & 63;
    const int wm = wave >> 1, wn = wave & 1;   // 2M x 2N wave grid
    const int lane15 = lane & 15;
    const int quad = lane >> 4;

    // staging: rows x 4 chunks (16B); A = 2 rounds of 64 rows, B = 4 rounds.
    // row = rr*64 + (tid>>2), logical chunk = tid&3;
    // swizzled source chunk = (tid&3) ^ ((row>>1)&3)  (rr-invariant).
    const int scol = (tid & 3) ^ ((tid >> 3) & 3);

    const unsigned short* aptr[2];
    const unsigned short* bptr[4];
#pragma unroll
    for (int rr = 0; rr < 2; ++rr) {
        int row = rr * 64 + (tid >> 2);
        const unsigned short* ab;
        if (MODE == 0) {
            int tok = row_token[m0 + row];
            ab = (tok < 0) ? zero_row : (A + (size_t)tok * KD);
        } else {
            ab = A + (size_t)(m0 + row) * KD;
        }
        aptr[rr] = ab + scol * 8;
    }
#pragma unroll
    for (int rr = 0; rr < 4; ++rr) {
        int row = rr * 64 + (tid >> 2);
        bptr[rr] = W + ((size_t)e * ND + (size_t)(n0 + row)) * (size_t)KD + scol * 8;
    }

    f32x4 acc[4][8];
#pragma unroll
    for (int i = 0; i < 4; ++i)
#pragma unroll
        for (int j = 0; j < 8; ++j) acc[i][j] = (f32x4)0.f;

    const int rowA = wm * 64 + lane15;      // + i*16 per fragment (4 frags)
    const int rowB = wn * 128 + lane15;     // + j*16 per fragment (8 frags)
    const int pcs = ((quad ^ ((lane15 >> 1) & 3)) * 8);  // physical chunk (shorts)

    auto stage = [&](int sb, int koff) {
#pragma unroll
        for (int rr = 0; rr < 2; ++rr)
            __builtin_amdgcn_global_load_lds(
                (const __attribute__((address_space(1))) void*)(aptr[rr] + koff),
                (__attribute__((address_space(3))) void*)(As + sb * 4096 + (rr * 256 + wave * 64) * 8), 16, 0, 0);
#pragma unroll
        for (int rr = 0; rr < 4; ++rr)
            __builtin_amdgcn_global_load_lds(
                (const __attribute__((address_space(1))) void*)(bptr[rr] + koff),
                (__attribute__((address_space(3))) void*)(Bs + sb * 8192 + (rr * 256 + wave * 64) * 8), 16, 0, 0);
    };

    // prologue: stage k0=0 into buffer 0
    stage(0, 0);

    int buf = 0;
    for (int k0 = 0; k0 < KD; k0 += 32) {
        __syncthreads();               // drains this iter's staged loads
        const int nbuf = buf ^ 1;
        if (k0 + 32 < KD) stage(nbuf, k0 + 32);
        bf16x8 af[4], bfv[8];
#pragma unroll
        for (int i = 0; i < 4; ++i)
            af[i] = *(const bf16x8*)(As + buf * 4096 + (rowA + i * 16) * 32 + pcs);
#pragma unroll
        for (int j = 0; j < 8; ++j)
            bfv[j] = *(const bf16x8*)(Bs + buf * 8192 + (rowB + j * 16) * 32 + pcs);
#pragma unroll
        for (int i = 0; i < 4; ++i)
#pragma unroll
            for (int j = 0; j < 8; ++j)
                acc[i][j] = __builtin_amdgcn_mfma_f32_16x16x32_bf16(af[i], bfv[j], acc[i][j], 0, 0, 0);
        buf = nbuf;
    }

    // epilogue
    float bv[8];
#pragma unroll
    for (int j = 0; j < 8; ++j)
        bv[j] = bias[e * ND + n0 + wn * 128 + j * 16 + lane15];
#pragma unroll
    for (int i = 0; i < 4; ++i) {
#pragma unroll
        for (int r4 = 0; r4 < 4; ++r4) {
            int m = m0 + wm * 64 + i * 16 + quad * 4 + r4;
            int tok = 0; float g = 0.f;
            if (MODE == 1) { tok = row_token[m]; g = row_gate[m]; }
#pragma unroll
            for (int j = 0; j < 8; ++j) {
                int n = n0 + wn * 128 + j * 16 + lane15;
                float v = acc[i][j][r4] + bv[j];
                if (MODE == 0) {
                    v = v > 0.f ? v : 0.1f * v;
                    Hout[(size_t)m * ND + n] = f2bf(v);
                } else {
                    if (tok >= 0) atomicAdd(Out + (size_t)tok * ND + n, g * v);
                }
            }
        }
    }
}

extern "C" void kernel_launch(void* const* d_in, const int* in_sizes, int n_in,
                              void* d_out, int out_size, void* d_ws, size_t ws_size,
                              hipStream_t stream) {
    const float* x  = (const float*)d_in[0];
    const float* wg = (const float*)d_in[1];
    const float* bg = (const float*)d_in[2];
    const float* w1 = (const float*)d_in[3];
    const float* b1 = (const float*)d_in[4];
    const float* w2 = (const float*)d_in[5];
    const float* b2 = (const float*)d_in[6];
    float* out0 = (float*)d_out;
    float* out_idx = out0 + (size_t)T_TOK * DMODEL;
    float* out_val = out_idx + T_TOK * TOPK;

    char* p = (char*)d_ws;
    auto alloc = [&](size_t bytes) {
        char* q = p;
        p += (bytes + 255) & ~(size_t)255;
        return q;
    };
    unsigned short* xb  = (unsigned short*)alloc((size_t)T_TOK * DMODEL * 2);
    unsigned short* w1b = (unsigned short*)alloc((size_t)NEXP * FFDIM * DMODEL * 2);
    unsigned short* w2b = (unsigned short*)alloc((size_t)NEXP * DMODEL * FFDIM * 2);
    unsigned short* hb  = (unsigned short*)alloc((size_t)ROWS_PAD * FFDIM * 2);
    unsigned short* zrow = (unsigned short*)alloc(DMODEL * 2);
    int* cnt = (int*)alloc(128);  // cnt[8] + fill[8]
    int* fill = cnt + 8;
    int* off_pad = (int*)alloc(64);
    int* tok_e = (int*)alloc((size_t)T_TOK * TOPK * 4);
    float* tok_g = (float*)alloc((size_t)T_TOK * TOPK * 4);
    int* row_token = (int*)alloc((size_t)ROWS_PAD * 4);
    float* row_gate = (float*)alloc((size_t)ROWS_PAD * 4);
    if ((size_t)(p - (char*)d_ws) > ws_size) return;  // ws too small: fail visibly, no OOB

    prep_kernel<<<4096, 256, 0, stream>>>(x, w1, w2, out0, xb, w1b, w2b,
                                          row_token, zrow, cnt);
    gate_kernel<<<T_TOK / 4, 256, 0, stream>>>(x, wg, bg, out_idx, out_val, tok_e, tok_g, cnt);
    offsets_kernel<<<1, 64, 0, stream>>>(cnt, off_pad);
    scatter_kernel<<<(T_TOK * TOPK + 255) / 256, 256, 0, stream>>>(tok_e, tok_g, off_pad, fill, row_token, row_gate);
    moe_gemm<0, DMODEL, FFDIM><<<dim3(MTILES, FFDIM / 256), 256, 0, stream>>>(
        xb, w1b, b1, row_token, row_gate, off_pad, zrow, hb, nullptr);
    moe_gemm<1, FFDIM, DMODEL><<<dim3(MTILES, DMODEL / 256), 256, 0, stream>>>(
        hb, w2b, b2, row_token, row_gate, off_pad, zrow, nullptr, out0);
}